// Round 7
// baseline (1771.893 us; speedup 1.0000x reference)
//
#include <hip/hip_runtime.h>
#include <hip/hip_fp16.h>

#define DF 96
#define BN_EPS 1e-3f
#define MAXNB 1024
#define PTILE 2048     // partition tile: 391 blocks at E=800k (occupancy!)
#define HTILE 2048     // hist tile

// ---------------- GEMM: C[N,96] = prologue(A)[N,96] @ W[96,96] ----------------
// 384 threads, 64-row tile, W staged in two 48-row halves (LDS 44.8 KB ->
// 3 blocks/CU = 18 waves/CU). prologue (FUSE_BN): a=relu(a)*s+t.
// HALF_OUT: epilogue converts to fp16. In-place (C==A, fp32) safe: block
// stages its own 64 rows into LDS before writing them.
template<bool FUSE_BN, bool HALF_OUT>
__global__ __launch_bounds__(384) void gemm_bn_kernel(
    const float* __restrict__ A, const float* __restrict__ W,
    const float* __restrict__ g, const float* __restrict__ b,
    const float* __restrict__ m, const float* __restrict__ v,
    void* __restrict__ Cout, int N)
{
    __shared__ float sW[48 * 96];      // half of W
    __shared__ float sA[64 * 100];
    __shared__ float sS[96], sT[96];

    const int tid  = threadIdx.x;
    const int row0 = blockIdx.x * 64;

    if (FUSE_BN && tid < 96) {
        float s = g[tid] * rsqrtf(v[tid] + BN_EPS);
        sS[tid] = s;
        sT[tid] = b[tid] - m[tid] * s;
    }
    __syncthreads();                   // sS/sT ready for A staging

    // stage A tile (64 rows): 1536 float4 / 384 = 4 per thread
    #pragma unroll
    for (int i = 0; i < 4; ++i) {
        int f   = tid + 384 * i;
        int row = f / 24;
        int cc  = (f % 24) * 4;
        int gr  = row0 + row;
        float4 val = make_float4(0.f, 0.f, 0.f, 0.f);
        if (gr < N) {
            val = *reinterpret_cast<const float4*>(A + (size_t)gr * DF + cc);
            if (FUSE_BN) {
                float* p = &val.x;
                #pragma unroll
                for (int j = 0; j < 4; ++j) {
                    float x_ = p[j];
                    x_ = x_ > 0.f ? x_ : 0.f;
                    p[j] = x_ * sS[cc + j] + sT[cc + j];
                }
            }
        }
        *reinterpret_cast<float4*>(sA + row * 100 + cc) = val;
    }

    const int tx = tid % 24, ty = tid / 24;   // ty in [0,16)
    const int c0 = tx * 4;
    float acc[4][4];
    #pragma unroll
    for (int i = 0; i < 4; ++i)
        for (int j = 0; j < 4; ++j) acc[i][j] = 0.f;

    const float4* Wv  = reinterpret_cast<const float4*>(W);
    float4*       sWv = reinterpret_cast<float4*>(sW);

    #pragma unroll
    for (int kh = 0; kh < 2; ++kh) {
        // stage W half: 1152 float4 / 384 = 3 per thread
        #pragma unroll
        for (int j = 0; j < 3; ++j)
            sWv[tid + 384 * j] = Wv[kh * 1152 + tid + 384 * j];
        __syncthreads();               // W half + (kh==0: A tile) ready

        const int kbase = kh * 48;
        for (int k = 0; k < 48; ++k) {
            float4 w4 = *reinterpret_cast<const float4*>(sW + k * 96 + c0);
            #pragma unroll
            for (int i = 0; i < 4; ++i) {
                float a = sA[(ty + 16 * i) * 100 + kbase + k];
                acc[i][0] = fmaf(a, w4.x, acc[i][0]);
                acc[i][1] = fmaf(a, w4.y, acc[i][1]);
                acc[i][2] = fmaf(a, w4.z, acc[i][2]);
                acc[i][3] = fmaf(a, w4.w, acc[i][3]);
            }
        }
        __syncthreads();               // all reads of sW done before re-stage
    }

    #pragma unroll
    for (int i = 0; i < 4; ++i) {
        int gr = row0 + ty + 16 * i;
        if (gr >= N) continue;
        if (HALF_OUT) {
            __half* C = (__half*)Cout;
            ushort4 u;
            u.x = __half_as_ushort(__float2half_rn(acc[i][0]));
            u.y = __half_as_ushort(__float2half_rn(acc[i][1]));
            u.z = __half_as_ushort(__float2half_rn(acc[i][2]));
            u.w = __half_as_ushort(__float2half_rn(acc[i][3]));
            *reinterpret_cast<ushort4*>(C + (size_t)gr * DF + c0) = u;
        } else {
            float* C = (float*)Cout;
            *reinterpret_cast<float4*>(C + (size_t)gr * DF + c0) =
                make_float4(acc[i][0], acc[i][1], acc[i][2], acc[i][3]);
        }
    }
}

// ---------------- CSR build (bucket = dst >> 6, low write-amp) ---------------
__global__ __launch_bounds__(256) void bucket_hist_kernel(
    const int* __restrict__ dst, int* __restrict__ bcnt, int E, int NB)
{
    __shared__ int lc[MAXNB];
    for (int i = threadIdx.x; i < NB; i += 256) lc[i] = 0;
    __syncthreads();
    int base = blockIdx.x * HTILE;
    #pragma unroll
    for (int j = 0; j < HTILE / 256; ++j) {
        int i = base + j * 256 + threadIdx.x;
        if (i < E) atomicAdd(&lc[dst[i] >> 6], 1);
    }
    __syncthreads();
    for (int i = threadIdx.x; i < NB; i += 256) {
        int c = lc[i];
        if (c) atomicAdd(&bcnt[i], c);
    }
}

__global__ __launch_bounds__(256) void bucket_scan_kernel(
    int* __restrict__ bbase, int* __restrict__ bcur, int NB)
{
    __shared__ int wsum[4];
    int t = threadIdx.x, lane = t & 63, wv = t >> 6;
    int vals[4], s = 0;
    #pragma unroll
    for (int j = 0; j < 4; ++j) {
        int idx = t * 4 + j;
        vals[j] = (idx < NB) ? bcur[idx] : 0;
        s += vals[j];
    }
    int inc = s;
    #pragma unroll
    for (int o = 1; o < 64; o <<= 1) {
        int u = __shfl_up(inc, o);
        if (lane >= o) inc += u;
    }
    int excl = inc - s;
    if (lane == 63) wsum[wv] = inc;
    __syncthreads();
    if (t == 0) {
        int run = 0;
        #pragma unroll
        for (int j = 0; j < 4; ++j) { int vv = wsum[j]; wsum[j] = run; run += vv; }
    }
    __syncthreads();
    int off = wsum[wv] + excl;
    #pragma unroll
    for (int j = 0; j < 4; ++j) {
        int idx = t * 4 + j;
        if (idx < NB) { bbase[idx] = off; bcur[idx] = off; off += vals[j]; }
    }
}

__global__ __launch_bounds__(256) void partition_kernel(
    const int* __restrict__ src, const int* __restrict__ dst,
    const float* __restrict__ ew, int* __restrict__ bcur,
    int2* __restrict__ ebufA, int E, int NB)
{
    __shared__ int lc[MAXNB];
    for (int i = threadIdx.x; i < NB; i += 256) lc[i] = 0;
    __syncthreads();
    int base = blockIdx.x * PTILE;
    #pragma unroll
    for (int j = 0; j < PTILE / 256; ++j) {
        int i = base + j * 256 + threadIdx.x;
        if (i < E) atomicAdd(&lc[dst[i] >> 6], 1);
    }
    __syncthreads();
    for (int i = threadIdx.x; i < NB; i += 256) {
        int c = lc[i];
        lc[i] = c ? atomicAdd(&bcur[i], c) : 0;
    }
    __syncthreads();
    #pragma unroll
    for (int j = 0; j < PTILE / 256; ++j) {
        int i = base + j * 256 + threadIdx.x;
        if (i < E) {
            int d   = dst[i];
            int bkt = d >> 6;
            int pos = atomicAdd(&lc[bkt], 1);
            ebufA[pos] = make_int2(src[i] | ((d & 63) << 26), __float_as_int(ew[i]));
        }
    }
}

__global__ __launch_bounds__(256) void csr_bucket_kernel(
    const int2* __restrict__ ebufA, const int* __restrict__ bbase,
    const int* __restrict__ bcur, int2* __restrict__ pairs,
    int* __restrict__ row_ptr, int N, int E, int NB)
{
    __shared__ int lc[64];
    int t   = threadIdx.x;
    int bkt = blockIdx.x;
    int e0  = bbase[bkt];
    int cnt = bcur[bkt] - e0;

    if (t < 64) lc[t] = 0;
    __syncthreads();
    for (int i = t; i < cnt; i += 256)
        atomicAdd(&lc[((unsigned)ebufA[e0 + i].x) >> 26], 1);
    __syncthreads();
    if (t < 64) {
        int v   = lc[t];
        int inc = v;
        #pragma unroll
        for (int o = 1; o < 64; o <<= 1) {
            int u = __shfl_up(inc, o);
            if (t >= o) inc += u;
        }
        int excl = inc - v;
        int node = (bkt << 6) + t;
        if (node < N) row_ptr[node] = e0 + excl;
        lc[t] = excl;
    }
    __syncthreads();
    for (int i = t; i < cnt; i += 256) {
        int2 p = ebufA[e0 + i];
        unsigned px = (unsigned)p.x;
        int pos = atomicAdd(&lc[px >> 26], 1);
        pairs[e0 + pos] = make_int2((int)(px & 0x03FFFFFFu), p.y);
    }
    if (bkt == NB - 1 && t == 0) row_ptr[N] = E;
}

// ---------------- Gather: agg[n][c] = sum_e w_e * h[src_e][c] ----------------
// 24 threads/node (4 cols each), 8 nodes per 192-thread block, 4-edge unroll.
// HALF: h rows are fp16 (192 B); FINAL: out = relu(acc)*s3 + t3 + x fused.
template<bool FINAL, bool HALF>
__global__ __launch_bounds__(192) void gather_kernel(
    const void* __restrict__ hbuf, const int2* __restrict__ pairs,
    const int* __restrict__ row_ptr, float* __restrict__ out,
    const float* __restrict__ xres,
    const float* __restrict__ g, const float* __restrict__ b,
    const float* __restrict__ m, const float* __restrict__ v, int N)
{
    __shared__ __attribute__((aligned(16))) float sS[96];
    __shared__ __attribute__((aligned(16))) float sT[96];
    if (FINAL) {
        int t = threadIdx.x;
        if (t < 96) {
            float s = g[t] * rsqrtf(v[t] + BN_EPS);
            sS[t] = s;
            sT[t] = b[t] - m[t] * s;
        }
        __syncthreads();
    }
    int node = blockIdx.x * 8 + threadIdx.x / 24;
    int q    = threadIdx.x % 24;
    if (node >= N) return;

    auto ld = [&](int srcR) -> float4 {
        if (HALF) {
            const __half* hp = (const __half*)hbuf + (size_t)srcR * DF + q * 4;
            float2 raw = *reinterpret_cast<const float2*>(hp);   // 4 halves
            union { float2 f; __half2 h[2]; } u; u.f = raw;
            float2 lo = __half22float2(u.h[0]);
            float2 hi = __half22float2(u.h[1]);
            return make_float4(lo.x, lo.y, hi.x, hi.y);
        } else {
            return *(reinterpret_cast<const float4*>(
                        (const float*)hbuf + (size_t)srcR * DF) + q);
        }
    };

    int e   = row_ptr[node];
    int end = row_ptr[node + 1];
    float ax = 0.f, ay = 0.f, az = 0.f, aw = 0.f;

    for (; e + 4 <= end; e += 4) {
        int2 p0 = pairs[e + 0];
        int2 p1 = pairs[e + 1];
        int2 p2 = pairs[e + 2];
        int2 p3 = pairs[e + 3];
        float4 v0 = ld(p0.x);
        float4 v1 = ld(p1.x);
        float4 v2 = ld(p2.x);
        float4 v3 = ld(p3.x);
        float w0 = __int_as_float(p0.y), w1 = __int_as_float(p1.y);
        float w2 = __int_as_float(p2.y), w3 = __int_as_float(p3.y);
        ax = fmaf(w0, v0.x, ax); ay = fmaf(w0, v0.y, ay);
        az = fmaf(w0, v0.z, az); aw = fmaf(w0, v0.w, aw);
        ax = fmaf(w1, v1.x, ax); ay = fmaf(w1, v1.y, ay);
        az = fmaf(w1, v1.z, az); aw = fmaf(w1, v1.w, aw);
        ax = fmaf(w2, v2.x, ax); ay = fmaf(w2, v2.y, ay);
        az = fmaf(w2, v2.z, az); aw = fmaf(w2, v2.w, aw);
        ax = fmaf(w3, v3.x, ax); ay = fmaf(w3, v3.y, ay);
        az = fmaf(w3, v3.z, az); aw = fmaf(w3, v3.w, aw);
    }
    for (; e < end; ++e) {
        int2 p = pairs[e];
        float4 hv = ld(p.x);
        float w = __int_as_float(p.y);
        ax = fmaf(w, hv.x, ax); ay = fmaf(w, hv.y, ay);
        az = fmaf(w, hv.z, az); aw = fmaf(w, hv.w, aw);
    }

    size_t o = (size_t)node * DF + q * 4;
    if (FINAL) {
        int c = q * 4;
        float4 xv = *reinterpret_cast<const float4*>(xres + o);
        float4 s4 = *reinterpret_cast<const float4*>(sS + c);
        float4 t4 = *reinterpret_cast<const float4*>(sT + c);
        float4 r;
        r.x = fmaf(fmaxf(ax, 0.f), s4.x, t4.x) + xv.x;
        r.y = fmaf(fmaxf(ay, 0.f), s4.y, t4.y) + xv.y;
        r.z = fmaf(fmaxf(az, 0.f), s4.z, t4.z) + xv.z;
        r.w = fmaf(fmaxf(aw, 0.f), s4.w, t4.w) + xv.w;
        *reinterpret_cast<float4*>(out + o) = r;
    } else {
        *reinterpret_cast<float4*>(out + o) = make_float4(ax, ay, az, aw);
    }
}

// ---------------- last-resort fallback: atomic scatter -----------------------
__global__ __launch_bounds__(256) void scatter_kernel(
    const float* __restrict__ h, const int* __restrict__ src,
    const int* __restrict__ dst, const float* __restrict__ ew,
    float* __restrict__ agg, int E)
{
    long long t = (long long)blockIdx.x * blockDim.x + threadIdx.x;
    if (t >= (long long)E * 24) return;
    int e  = (int)(t / 24);
    int cc = (int)(t % 24) * 4;
    int s  = src[e];
    int d  = dst[e];
    float w = ew[e];
    float4 hv = *reinterpret_cast<const float4*>(h + (size_t)s * DF + cc);
    float* out = agg + (size_t)d * DF + cc;
    atomicAdd(out + 0, w * hv.x);
    atomicAdd(out + 1, w * hv.y);
    atomicAdd(out + 2, w * hv.z);
    atomicAdd(out + 3, w * hv.w);
}

__global__ __launch_bounds__(256) void final_kernel(
    const float* __restrict__ agg, const float* __restrict__ x,
    const float* __restrict__ g, const float* __restrict__ b,
    const float* __restrict__ m, const float* __restrict__ v,
    float* __restrict__ out, int total4)
{
    int i = blockIdx.x * blockDim.x + threadIdx.x;
    if (i >= total4) return;
    int cc = (i % 24) * 4;
    float4 a4 = reinterpret_cast<const float4*>(agg)[i];
    float4 x4 = reinterpret_cast<const float4*>(x)[i];
    float* pa = &a4.x;
    const float* px = &x4.x;
    float4 o;
    float* po = &o.x;
    #pragma unroll
    for (int j = 0; j < 4; ++j) {
        int c = cc + j;
        float s  = g[c] * rsqrtf(v[c] + BN_EPS);
        float tt = b[c] - m[c] * s;
        float a  = pa[j] > 0.f ? pa[j] : 0.f;
        po[j] = a * s + tt + px[j];
    }
    reinterpret_cast<float4*>(out)[i] = o;
}

extern "C" void kernel_launch(void* const* d_in, const int* in_sizes, int n_in,
                              void* d_out, int out_size, void* d_ws, size_t ws_size,
                              hipStream_t stream)
{
    const float* x    = (const float*)d_in[0];
    const int*   esrc = (const int*)d_in[1];
    const int*   edst = (const int*)d_in[2];
    const float* ew   = (const float*)d_in[3];
    const float* w1   = (const float*)d_in[4];
    const float* w2   = (const float*)d_in[5];
    const float* w3   = (const float*)d_in[6];
    const float* g1 = (const float*)d_in[7],  *b1 = (const float*)d_in[8];
    const float* m1 = (const float*)d_in[9],  *v1 = (const float*)d_in[10];
    const float* g2 = (const float*)d_in[11], *b2 = (const float*)d_in[12];
    const float* m2 = (const float*)d_in[13], *v2 = (const float*)d_in[14];
    const float* g3 = (const float*)d_in[15], *b3 = (const float*)d_in[16];
    const float* m3 = (const float*)d_in[17], *v3 = (const float*)d_in[18];

    const int N  = in_sizes[0] / DF;   // 50000
    const int E  = in_sizes[1];        // 800000
    const int NB = (N + 63) >> 6;      // 782 buckets
    const size_t nbytes = (size_t)N * DF * sizeof(float);
    const size_t hh_bytes = (size_t)N * DF * 2;

    float* B = (float*)d_out;

    auto up = [](size_t s) { return (s + 255) & ~(size_t)255; };
    size_t off_agg   = 0;
    size_t off_pairs = off_agg   + up(nbytes);
    size_t off_rptr  = off_pairs + up((size_t)E * 8);
    size_t off_bbase = off_rptr  + up(((size_t)N + 1) * 4);
    size_t off_bcur  = off_bbase + up((size_t)NB * 4);
    size_t off_ebufA = off_bcur  + up((size_t)NB * 4);   // ebufA last; Hh aliases it
    size_t need_f32  = off_ebufA + up((size_t)E * 8);
    size_t ovl       = (size_t)E * 8 > hh_bytes ? (size_t)E * 8 : hh_bytes;
    size_t need_f16  = off_ebufA + up(ovl);

    char*  ws = (char*)d_ws;
    float* A  = (float*)(ws + off_agg);

    const int gemm_grid = (N + 63) / 64;
    const bool ok = (NB <= MAXNB) && (N < (1 << 26)) && (ws_size >= need_f32);

    if (ok) {
        int2*   ebufA  = (int2*)(ws + off_ebufA);
        __half* Hh     = (__half*)(ws + off_ebufA);   // alias: ebufA dead after csr
        int2*   pairs  = (int2*)(ws + off_pairs);
        int*    rowptr = (int*) (ws + off_rptr);
        int*    bbase  = (int*) (ws + off_bbase);
        int*    bcur   = (int*) (ws + off_bcur);
        const bool half_h = (ws_size >= need_f16);

        // ---- CSR build (once): bucket hist -> scan -> partition -> sort ----
        hipMemsetAsync(bcur, 0, (size_t)NB * 4, stream);
        bucket_hist_kernel<<<(E + HTILE - 1) / HTILE, 256, 0, stream>>>(
            edst, bcur, E, NB);
        bucket_scan_kernel<<<1, 256, 0, stream>>>(bbase, bcur, NB);
        partition_kernel<<<(E + PTILE - 1) / PTILE, 256, 0, stream>>>(
            esrc, edst, ew, bcur, ebufA, E, NB);
        csr_bucket_kernel<<<NB, 256, 0, stream>>>(
            ebufA, bbase, bcur, pairs, rowptr, N, E, NB);

        const int ggrid = (N + 7) / 8;

        if (half_h) {
            // h lives in ws as fp16 (over dead ebufA); d_out written at end
            gemm_bn_kernel<false, true><<<gemm_grid, 384, 0, stream>>>(
                x, w1, nullptr, nullptr, nullptr, nullptr, Hh, N);
            gather_kernel<false, true><<<ggrid, 192, 0, stream>>>(
                Hh, pairs, rowptr, A, nullptr, nullptr, nullptr, nullptr, nullptr, N);
            gemm_bn_kernel<true, true><<<gemm_grid, 384, 0, stream>>>(
                A, w2, g1, b1, m1, v1, Hh, N);
            gather_kernel<false, true><<<ggrid, 192, 0, stream>>>(
                Hh, pairs, rowptr, A, nullptr, nullptr, nullptr, nullptr, nullptr, N);
            gemm_bn_kernel<true, true><<<gemm_grid, 384, 0, stream>>>(
                A, w3, g2, b2, m2, v2, Hh, N);
            gather_kernel<true, true><<<ggrid, 192, 0, stream>>>(
                Hh, pairs, rowptr, B, x, g3, b3, m3, v3, N);
        } else {
            // fp32 h in d_out
            gemm_bn_kernel<false, false><<<gemm_grid, 384, 0, stream>>>(
                x, w1, nullptr, nullptr, nullptr, nullptr, B, N);
            gather_kernel<false, false><<<ggrid, 192, 0, stream>>>(
                B, pairs, rowptr, A, nullptr, nullptr, nullptr, nullptr, nullptr, N);
            gemm_bn_kernel<true, false><<<gemm_grid, 384, 0, stream>>>(
                A, w2, g1, b1, m1, v1, B, N);
            gather_kernel<false, false><<<ggrid, 192, 0, stream>>>(
                B, pairs, rowptr, A, nullptr, nullptr, nullptr, nullptr, nullptr, N);
            gemm_bn_kernel<true, false><<<gemm_grid, 384, 0, stream>>>(
                A, w3, g2, b2, m2, v2, A, N);
            gather_kernel<true, false><<<ggrid, 192, 0, stream>>>(
                A, pairs, rowptr, B, x, g3, b3, m3, v3, N);
        }
    } else {
        // last-resort: atomic scatter path
        const long long st     = (long long)E * 24;
        const int scatter_grid = (int)((st + 255) / 256);
        const int total4       = N * 24;
        const int final_grid   = (total4 + 255) / 256;

        hipMemsetAsync(A, 0, nbytes, stream);
        gemm_bn_kernel<false, false><<<gemm_grid, 384, 0, stream>>>(
            x, w1, nullptr, nullptr, nullptr, nullptr, B, N);
        scatter_kernel<<<scatter_grid, 256, 0, stream>>>(B, esrc, edst, ew, A, E);

        gemm_bn_kernel<true, false><<<gemm_grid, 384, 0, stream>>>(
            A, w2, g1, b1, m1, v1, B, N);
        hipMemsetAsync(A, 0, nbytes, stream);
        scatter_kernel<<<scatter_grid, 256, 0, stream>>>(B, esrc, edst, ew, A, E);

        gemm_bn_kernel<true, false><<<gemm_grid, 384, 0, stream>>>(
            A, w3, g2, b2, m2, v2, B, N);
        hipMemsetAsync(A, 0, nbytes, stream);
        scatter_kernel<<<scatter_grid, 256, 0, stream>>>(B, esrc, edst, ew, A, E);

        final_kernel<<<final_grid, 256, 0, stream>>>(
            A, x, g3, b3, m3, v3, (float*)d_out, total4);
    }
}

// Round 8
// 216.683 us; speedup vs baseline: 8.1774x; 8.1774x over previous
//
#include <hip/hip_runtime.h>
#include <hip/hip_fp16.h>

#define DF 96
#define BN_EPS 1e-3f
#define MAXNB 1024
#define PTILE 2048     // partition tile: 391 blocks at E=800k (occupancy)
#define HTILE 2048     // hist tile

// ---------------- GEMM: C[N,96] = prologue(A)[N,96] @ W[96,96] ----------------
// PROVEN round-6 version (192 threads, ~16us, no spill). Do not "optimize"
// without checking -Rpass-analysis scratch first (round-7 spill disaster:
// 949MB fetch/628MB write per dispatch from acc spills).
// prologue (FUSE_BN): a = relu(a)*s[c] + t[c]; HALF_OUT: fp16 epilogue.
// In-place (C==A, fp32) safe: block stages its own 64 rows into LDS first.
template<bool FUSE_BN, bool HALF_OUT>
__global__ __launch_bounds__(192) void gemm_bn_kernel(
    const float* __restrict__ A, const float* __restrict__ W,
    const float* __restrict__ g, const float* __restrict__ b,
    const float* __restrict__ m, const float* __restrict__ v,
    void* __restrict__ Cout, int N)
{
    __shared__ float sW[96 * 96];
    __shared__ float sA[64 * 100];
    __shared__ float sS[96], sT[96];

    const int tid  = threadIdx.x;
    const int row0 = blockIdx.x * 64;

    if (FUSE_BN && tid < 96) {
        float s = g[tid] * rsqrtf(v[tid] + BN_EPS);
        sS[tid] = s;
        sT[tid] = b[tid] - m[tid] * s;
    }
    {
        const float4* Wv  = reinterpret_cast<const float4*>(W);
        float4*       sWv = reinterpret_cast<float4*>(sW);
        #pragma unroll
        for (int i = 0; i < 12; ++i) sWv[tid + 192 * i] = Wv[tid + 192 * i];
    }
    __syncthreads();

    #pragma unroll
    for (int i = 0; i < 8; ++i) {
        int f   = tid + 192 * i;
        int row = f / 24;
        int cc  = (f % 24) * 4;
        int gr  = row0 + row;
        float4 val = make_float4(0.f, 0.f, 0.f, 0.f);
        if (gr < N) {
            val = *reinterpret_cast<const float4*>(A + (size_t)gr * DF + cc);
            if (FUSE_BN) {
                float* p = &val.x;
                #pragma unroll
                for (int j = 0; j < 4; ++j) {
                    float x_ = p[j];
                    x_ = x_ > 0.f ? x_ : 0.f;
                    p[j] = x_ * sS[cc + j] + sT[cc + j];
                }
            }
        }
        *reinterpret_cast<float4*>(sA + row * 100 + cc) = val;
    }
    __syncthreads();

    const int tx = tid % 24, ty = tid / 24;
    const int c0 = tx * 4;
    float acc[8][4];
    #pragma unroll
    for (int i = 0; i < 8; ++i)
        for (int j = 0; j < 4; ++j) acc[i][j] = 0.f;

    for (int k = 0; k < 96; ++k) {
        float4 w4 = *reinterpret_cast<const float4*>(sW + k * 96 + c0);
        #pragma unroll
        for (int i = 0; i < 8; ++i) {
            float a = sA[(ty + 8 * i) * 100 + k];
            acc[i][0] += a * w4.x;
            acc[i][1] += a * w4.y;
            acc[i][2] += a * w4.z;
            acc[i][3] += a * w4.w;
        }
    }
    #pragma unroll
    for (int i = 0; i < 8; ++i) {
        int gr = row0 + ty + 8 * i;
        if (gr >= N) continue;
        if (HALF_OUT) {
            __half* C = (__half*)Cout;
            ushort4 u;
            u.x = __half_as_ushort(__float2half_rn(acc[i][0]));
            u.y = __half_as_ushort(__float2half_rn(acc[i][1]));
            u.z = __half_as_ushort(__float2half_rn(acc[i][2]));
            u.w = __half_as_ushort(__float2half_rn(acc[i][3]));
            *reinterpret_cast<ushort4*>(C + (size_t)gr * DF + c0) = u;
        } else {
            float* C = (float*)Cout;
            *reinterpret_cast<float4*>(C + (size_t)gr * DF + c0) =
                make_float4(acc[i][0], acc[i][1], acc[i][2], acc[i][3]);
        }
    }
}

// ---------------- CSR build (bucket = dst >> 6, low write-amp) ---------------
__global__ __launch_bounds__(256) void bucket_hist_kernel(
    const int* __restrict__ dst, int* __restrict__ bcnt, int E, int NB)
{
    __shared__ int lc[MAXNB];
    for (int i = threadIdx.x; i < NB; i += 256) lc[i] = 0;
    __syncthreads();
    int base = blockIdx.x * HTILE;
    #pragma unroll
    for (int j = 0; j < HTILE / 256; ++j) {
        int i = base + j * 256 + threadIdx.x;
        if (i < E) atomicAdd(&lc[dst[i] >> 6], 1);
    }
    __syncthreads();
    for (int i = threadIdx.x; i < NB; i += 256) {
        int c = lc[i];
        if (c) atomicAdd(&bcnt[i], c);
    }
}

__global__ __launch_bounds__(256) void bucket_scan_kernel(
    int* __restrict__ bbase, int* __restrict__ bcur, int NB)
{
    __shared__ int wsum[4];
    int t = threadIdx.x, lane = t & 63, wv = t >> 6;
    int vals[4], s = 0;
    #pragma unroll
    for (int j = 0; j < 4; ++j) {
        int idx = t * 4 + j;
        vals[j] = (idx < NB) ? bcur[idx] : 0;
        s += vals[j];
    }
    int inc = s;
    #pragma unroll
    for (int o = 1; o < 64; o <<= 1) {
        int u = __shfl_up(inc, o);
        if (lane >= o) inc += u;
    }
    int excl = inc - s;
    if (lane == 63) wsum[wv] = inc;
    __syncthreads();
    if (t == 0) {
        int run = 0;
        #pragma unroll
        for (int j = 0; j < 4; ++j) { int vv = wsum[j]; wsum[j] = run; run += vv; }
    }
    __syncthreads();
    int off = wsum[wv] + excl;
    #pragma unroll
    for (int j = 0; j < 4; ++j) {
        int idx = t * 4 + j;
        if (idx < NB) { bbase[idx] = off; bcur[idx] = off; off += vals[j]; }
    }
}

__global__ __launch_bounds__(256) void partition_kernel(
    const int* __restrict__ src, const int* __restrict__ dst,
    const float* __restrict__ ew, int* __restrict__ bcur,
    int2* __restrict__ ebufA, int E, int NB)
{
    __shared__ int lc[MAXNB];
    for (int i = threadIdx.x; i < NB; i += 256) lc[i] = 0;
    __syncthreads();
    int base = blockIdx.x * PTILE;
    #pragma unroll
    for (int j = 0; j < PTILE / 256; ++j) {
        int i = base + j * 256 + threadIdx.x;
        if (i < E) atomicAdd(&lc[dst[i] >> 6], 1);
    }
    __syncthreads();
    for (int i = threadIdx.x; i < NB; i += 256) {
        int c = lc[i];
        lc[i] = c ? atomicAdd(&bcur[i], c) : 0;
    }
    __syncthreads();
    #pragma unroll
    for (int j = 0; j < PTILE / 256; ++j) {
        int i = base + j * 256 + threadIdx.x;
        if (i < E) {
            int d   = dst[i];
            int bkt = d >> 6;
            int pos = atomicAdd(&lc[bkt], 1);
            ebufA[pos] = make_int2(src[i] | ((d & 63) << 26), __float_as_int(ew[i]));
        }
    }
}

__global__ __launch_bounds__(256) void csr_bucket_kernel(
    const int2* __restrict__ ebufA, const int* __restrict__ bbase,
    const int* __restrict__ bcur, int2* __restrict__ pairs,
    int* __restrict__ row_ptr, int N, int E, int NB)
{
    __shared__ int lc[64];
    int t   = threadIdx.x;
    int bkt = blockIdx.x;
    int e0  = bbase[bkt];
    int cnt = bcur[bkt] - e0;

    if (t < 64) lc[t] = 0;
    __syncthreads();
    for (int i = t; i < cnt; i += 256)
        atomicAdd(&lc[((unsigned)ebufA[e0 + i].x) >> 26], 1);
    __syncthreads();
    if (t < 64) {
        int v   = lc[t];
        int inc = v;
        #pragma unroll
        for (int o = 1; o < 64; o <<= 1) {
            int u = __shfl_up(inc, o);
            if (t >= o) inc += u;
        }
        int excl = inc - v;
        int node = (bkt << 6) + t;
        if (node < N) row_ptr[node] = e0 + excl;
        lc[t] = excl;
    }
    __syncthreads();
    for (int i = t; i < cnt; i += 256) {
        int2 p = ebufA[e0 + i];
        unsigned px = (unsigned)p.x;
        int pos = atomicAdd(&lc[px >> 26], 1);
        pairs[e0 + pos] = make_int2((int)(px & 0x03FFFFFFu), p.y);
    }
    if (bkt == NB - 1 && t == 0) row_ptr[N] = E;
}

// ---------------- Gather: agg[n][c] = sum_e w_e * h[src_e][c] ----------------
// 24 threads/node (4 cols each), 8 nodes per 192-thread block, 4-edge unroll.
// HALF: h rows are fp16 (192 B); FINAL: out = relu(acc)*s3 + t3 + x fused.
template<bool FINAL, bool HALF>
__global__ __launch_bounds__(192) void gather_kernel(
    const void* __restrict__ hbuf, const int2* __restrict__ pairs,
    const int* __restrict__ row_ptr, float* __restrict__ out,
    const float* __restrict__ xres,
    const float* __restrict__ g, const float* __restrict__ b,
    const float* __restrict__ m, const float* __restrict__ v, int N)
{
    __shared__ __attribute__((aligned(16))) float sS[96];
    __shared__ __attribute__((aligned(16))) float sT[96];
    if (FINAL) {
        int t = threadIdx.x;
        if (t < 96) {
            float s = g[t] * rsqrtf(v[t] + BN_EPS);
            sS[t] = s;
            sT[t] = b[t] - m[t] * s;
        }
        __syncthreads();
    }
    int node = blockIdx.x * 8 + threadIdx.x / 24;
    int q    = threadIdx.x % 24;
    if (node >= N) return;

    auto ld = [&](int srcR) -> float4 {
        if (HALF) {
            const __half* hp = (const __half*)hbuf + (size_t)srcR * DF + q * 4;
            float2 raw = *reinterpret_cast<const float2*>(hp);   // 4 halves
            union { float2 f; __half2 h[2]; } u; u.f = raw;
            float2 lo = __half22float2(u.h[0]);
            float2 hi = __half22float2(u.h[1]);
            return make_float4(lo.x, lo.y, hi.x, hi.y);
        } else {
            return *(reinterpret_cast<const float4*>(
                        (const float*)hbuf + (size_t)srcR * DF) + q);
        }
    };

    int e   = row_ptr[node];
    int end = row_ptr[node + 1];
    float ax = 0.f, ay = 0.f, az = 0.f, aw = 0.f;

    for (; e + 4 <= end; e += 4) {
        int2 p0 = pairs[e + 0];
        int2 p1 = pairs[e + 1];
        int2 p2 = pairs[e + 2];
        int2 p3 = pairs[e + 3];
        float4 v0 = ld(p0.x);
        float4 v1 = ld(p1.x);
        float4 v2 = ld(p2.x);
        float4 v3 = ld(p3.x);
        float w0 = __int_as_float(p0.y), w1 = __int_as_float(p1.y);
        float w2 = __int_as_float(p2.y), w3 = __int_as_float(p3.y);
        ax = fmaf(w0, v0.x, ax); ay = fmaf(w0, v0.y, ay);
        az = fmaf(w0, v0.z, az); aw = fmaf(w0, v0.w, aw);
        ax = fmaf(w1, v1.x, ax); ay = fmaf(w1, v1.y, ay);
        az = fmaf(w1, v1.z, az); aw = fmaf(w1, v1.w, aw);
        ax = fmaf(w2, v2.x, ax); ay = fmaf(w2, v2.y, ay);
        az = fmaf(w2, v2.z, az); aw = fmaf(w2, v2.w, aw);
        ax = fmaf(w3, v3.x, ax); ay = fmaf(w3, v3.y, ay);
        az = fmaf(w3, v3.z, az); aw = fmaf(w3, v3.w, aw);
    }
    for (; e < end; ++e) {
        int2 p = pairs[e];
        float4 hv = ld(p.x);
        float w = __int_as_float(p.y);
        ax = fmaf(w, hv.x, ax); ay = fmaf(w, hv.y, ay);
        az = fmaf(w, hv.z, az); aw = fmaf(w, hv.w, aw);
    }

    size_t o = (size_t)node * DF + q * 4;
    if (FINAL) {
        int c = q * 4;
        float4 xv = *reinterpret_cast<const float4*>(xres + o);
        float4 s4 = *reinterpret_cast<const float4*>(sS + c);
        float4 t4 = *reinterpret_cast<const float4*>(sT + c);
        float4 r;
        r.x = fmaf(fmaxf(ax, 0.f), s4.x, t4.x) + xv.x;
        r.y = fmaf(fmaxf(ay, 0.f), s4.y, t4.y) + xv.y;
        r.z = fmaf(fmaxf(az, 0.f), s4.z, t4.z) + xv.z;
        r.w = fmaf(fmaxf(aw, 0.f), s4.w, t4.w) + xv.w;
        *reinterpret_cast<float4*>(out + o) = r;
    } else {
        *reinterpret_cast<float4*>(out + o) = make_float4(ax, ay, az, aw);
    }
}

// ---------------- last-resort fallback: atomic scatter -----------------------
__global__ __launch_bounds__(256) void scatter_kernel(
    const float* __restrict__ h, const int* __restrict__ src,
    const int* __restrict__ dst, const float* __restrict__ ew,
    float* __restrict__ agg, int E)
{
    long long t = (long long)blockIdx.x * blockDim.x + threadIdx.x;
    if (t >= (long long)E * 24) return;
    int e  = (int)(t / 24);
    int cc = (int)(t % 24) * 4;
    int s  = src[e];
    int d  = dst[e];
    float w = ew[e];
    float4 hv = *reinterpret_cast<const float4*>(h + (size_t)s * DF + cc);
    float* out = agg + (size_t)d * DF + cc;
    atomicAdd(out + 0, w * hv.x);
    atomicAdd(out + 1, w * hv.y);
    atomicAdd(out + 2, w * hv.z);
    atomicAdd(out + 3, w * hv.w);
}

__global__ __launch_bounds__(256) void final_kernel(
    const float* __restrict__ agg, const float* __restrict__ x,
    const float* __restrict__ g, const float* __restrict__ b,
    const float* __restrict__ m, const float* __restrict__ v,
    float* __restrict__ out, int total4)
{
    int i = blockIdx.x * blockDim.x + threadIdx.x;
    if (i >= total4) return;
    int cc = (i % 24) * 4;
    float4 a4 = reinterpret_cast<const float4*>(agg)[i];
    float4 x4 = reinterpret_cast<const float4*>(x)[i];
    float* pa = &a4.x;
    const float* px = &x4.x;
    float4 o;
    float* po = &o.x;
    #pragma unroll
    for (int j = 0; j < 4; ++j) {
        int c = cc + j;
        float s  = g[c] * rsqrtf(v[c] + BN_EPS);
        float tt = b[c] - m[c] * s;
        float a  = pa[j] > 0.f ? pa[j] : 0.f;
        po[j] = a * s + tt + px[j];
    }
    reinterpret_cast<float4*>(out)[i] = o;
}

extern "C" void kernel_launch(void* const* d_in, const int* in_sizes, int n_in,
                              void* d_out, int out_size, void* d_ws, size_t ws_size,
                              hipStream_t stream)
{
    const float* x    = (const float*)d_in[0];
    const int*   esrc = (const int*)d_in[1];
    const int*   edst = (const int*)d_in[2];
    const float* ew   = (const float*)d_in[3];
    const float* w1   = (const float*)d_in[4];
    const float* w2   = (const float*)d_in[5];
    const float* w3   = (const float*)d_in[6];
    const float* g1 = (const float*)d_in[7],  *b1 = (const float*)d_in[8];
    const float* m1 = (const float*)d_in[9],  *v1 = (const float*)d_in[10];
    const float* g2 = (const float*)d_in[11], *b2 = (const float*)d_in[12];
    const float* m2 = (const float*)d_in[13], *v2 = (const float*)d_in[14];
    const float* g3 = (const float*)d_in[15], *b3 = (const float*)d_in[16];
    const float* m3 = (const float*)d_in[17], *v3 = (const float*)d_in[18];

    const int N  = in_sizes[0] / DF;   // 50000
    const int E  = in_sizes[1];        // 800000
    const int NB = (N + 63) >> 6;      // 782 buckets
    const size_t nbytes = (size_t)N * DF * sizeof(float);
    const size_t hh_bytes = (size_t)N * DF * 2;

    float* B = (float*)d_out;

    auto up = [](size_t s) { return (s + 255) & ~(size_t)255; };
    size_t off_agg   = 0;
    size_t off_pairs = off_agg   + up(nbytes);
    size_t off_rptr  = off_pairs + up((size_t)E * 8);
    size_t off_bbase = off_rptr  + up(((size_t)N + 1) * 4);
    size_t off_bcur  = off_bbase + up((size_t)NB * 4);
    size_t off_ebufA = off_bcur  + up((size_t)NB * 4);   // ebufA last; Hh aliases it
    size_t need_f32  = off_ebufA + up((size_t)E * 8);
    size_t ovl       = (size_t)E * 8 > hh_bytes ? (size_t)E * 8 : hh_bytes;
    size_t need_f16  = off_ebufA + up(ovl);

    char*  ws = (char*)d_ws;
    float* A  = (float*)(ws + off_agg);

    const int gemm_grid = (N + 63) / 64;
    const bool ok = (NB <= MAXNB) && (N < (1 << 26)) && (ws_size >= need_f32);

    if (ok) {
        int2*   ebufA  = (int2*)(ws + off_ebufA);
        __half* Hh     = (__half*)(ws + off_ebufA);   // alias: ebufA dead after csr
        int2*   pairs  = (int2*)(ws + off_pairs);
        int*    rowptr = (int*) (ws + off_rptr);
        int*    bbase  = (int*) (ws + off_bbase);
        int*    bcur   = (int*) (ws + off_bcur);
        const bool half_h = (ws_size >= need_f16);

        // ---- CSR build (once): bucket hist -> scan -> partition -> sort ----
        hipMemsetAsync(bcur, 0, (size_t)NB * 4, stream);
        bucket_hist_kernel<<<(E + HTILE - 1) / HTILE, 256, 0, stream>>>(
            edst, bcur, E, NB);
        bucket_scan_kernel<<<1, 256, 0, stream>>>(bbase, bcur, NB);
        partition_kernel<<<(E + PTILE - 1) / PTILE, 256, 0, stream>>>(
            esrc, edst, ew, bcur, ebufA, E, NB);
        csr_bucket_kernel<<<NB, 256, 0, stream>>>(
            ebufA, bbase, bcur, pairs, rowptr, N, E, NB);

        const int ggrid = (N + 7) / 8;

        if (half_h) {
            // h lives in ws as fp16 (over dead ebufA); d_out written at end
            gemm_bn_kernel<false, true><<<gemm_grid, 192, 0, stream>>>(
                x, w1, nullptr, nullptr, nullptr, nullptr, Hh, N);
            gather_kernel<false, true><<<ggrid, 192, 0, stream>>>(
                Hh, pairs, rowptr, A, nullptr, nullptr, nullptr, nullptr, nullptr, N);
            gemm_bn_kernel<true, true><<<gemm_grid, 192, 0, stream>>>(
                A, w2, g1, b1, m1, v1, Hh, N);
            gather_kernel<false, true><<<ggrid, 192, 0, stream>>>(
                Hh, pairs, rowptr, A, nullptr, nullptr, nullptr, nullptr, nullptr, N);
            gemm_bn_kernel<true, true><<<gemm_grid, 192, 0, stream>>>(
                A, w3, g2, b2, m2, v2, Hh, N);
            gather_kernel<true, true><<<ggrid, 192, 0, stream>>>(
                Hh, pairs, rowptr, B, x, g3, b3, m3, v3, N);
        } else {
            // fp32 h in d_out
            gemm_bn_kernel<false, false><<<gemm_grid, 192, 0, stream>>>(
                x, w1, nullptr, nullptr, nullptr, nullptr, B, N);
            gather_kernel<false, false><<<ggrid, 192, 0, stream>>>(
                B, pairs, rowptr, A, nullptr, nullptr, nullptr, nullptr, nullptr, N);
            gemm_bn_kernel<true, false><<<gemm_grid, 192, 0, stream>>>(
                A, w2, g1, b1, m1, v1, B, N);
            gather_kernel<false, false><<<ggrid, 192, 0, stream>>>(
                B, pairs, rowptr, A, nullptr, nullptr, nullptr, nullptr, nullptr, N);
            gemm_bn_kernel<true, false><<<gemm_grid, 192, 0, stream>>>(
                A, w3, g2, b2, m2, v2, A, N);
            gather_kernel<true, false><<<ggrid, 192, 0, stream>>>(
                A, pairs, rowptr, B, x, g3, b3, m3, v3, N);
        }
    } else {
        // last-resort: atomic scatter path
        const long long st     = (long long)E * 24;
        const int scatter_grid = (int)((st + 255) / 256);
        const int total4       = N * 24;
        const int final_grid   = (total4 + 255) / 256;

        hipMemsetAsync(A, 0, nbytes, stream);
        gemm_bn_kernel<false, false><<<gemm_grid, 192, 0, stream>>>(
            x, w1, nullptr, nullptr, nullptr, nullptr, B, N);
        scatter_kernel<<<scatter_grid, 256, 0, stream>>>(B, esrc, edst, ew, A, E);

        gemm_bn_kernel<true, false><<<gemm_grid, 192, 0, stream>>>(
            A, w2, g1, b1, m1, v1, B, N);
        hipMemsetAsync(A, 0, nbytes, stream);
        scatter_kernel<<<scatter_grid, 256, 0, stream>>>(B, esrc, edst, ew, A, E);

        gemm_bn_kernel<true, false><<<gemm_grid, 192, 0, stream>>>(
            A, w3, g2, b2, m2, v2, B, N);
        hipMemsetAsync(A, 0, nbytes, stream);
        scatter_kernel<<<scatter_grid, 256, 0, stream>>>(B, esrc, edst, ew, A, E);

        final_kernel<<<final_grid, 256, 0, stream>>>(
            A, x, g3, b3, m3, v3, (float*)d_out, total4);
    }
}